// Round 1
// baseline (2556.291 us; speedup 1.0000x reference)
//
#include <hip/hip_runtime.h>

#define NUM_USERS 100000
#define NUM_ITEMS 50000
#define NUM_EDGES 2000000
#define EMB_D 64
#define N_TOTAL (NUM_USERS + NUM_ITEMS)

// ---------------------------------------------------------------------------
// Pass 1: user degree = segment_sum(edge_values, edge_users)
// ---------------------------------------------------------------------------
__global__ void deg_kernel(const float* __restrict__ ev,
                           const int* __restrict__ eu,
                           float* __restrict__ deg) {
    int i = blockIdx.x * blockDim.x + threadIdx.x;
    if (i < NUM_EDGES) {
        atomicAdd(&deg[eu[i]], ev[i]);
    }
}

// inv[u] = 1/sqrt(deg[u] + 1e-6), in place
__global__ void inv_kernel(float* __restrict__ deg) {
    int i = blockIdx.x * blockDim.x + threadIdx.x;
    if (i < NUM_USERS) {
        deg[i] = rsqrtf(deg[i] + 1e-6f);
    }
}

// ---------------------------------------------------------------------------
// SpMM layer: out[u]    += w_e * in[U+i]
//             out[U+i]  += w_e * in[u]
// where w_e = edge_values[e] * inv_sqrt_deg[edge_users[e]].
// One 64-lane wave per edge; lane = embedding dim. Rows are 256B contiguous
// so both gathers and both atomic scatters are fully coalesced per wave.
// in_u / in_i may point into the same [N_TOTAL][64] buffer or the two
// original input matrices (layer 1).
// ---------------------------------------------------------------------------
__global__ __launch_bounds__(256) void spmm_kernel(
        const float* __restrict__ in_u,   // [NUM_USERS][64]
        const float* __restrict__ in_i,   // [NUM_ITEMS][64]
        const float* __restrict__ ev,     // [NUM_EDGES]
        const int* __restrict__ eu,       // [NUM_EDGES]
        const int* __restrict__ ei,       // [NUM_EDGES]
        const float* __restrict__ inv,    // [NUM_USERS] (inv sqrt degree)
        float* __restrict__ out) {        // [N_TOTAL][64], pre-zeroed
    const int lane = threadIdx.x & 63;
    const int e = blockIdx.x * (blockDim.x >> 6) + (threadIdx.x >> 6);
    if (e >= NUM_EDGES) return;

    const int u  = eu[e];
    const int it = ei[e];
    const float w = ev[e] * inv[u];

    const float xu = in_u[(size_t)u * EMB_D + lane];
    const float xi = in_i[(size_t)it * EMB_D + lane];

    atomicAdd(&out[(size_t)u * EMB_D + lane], w * xi);
    atomicAdd(&out[((size_t)NUM_USERS + it) * EMB_D + lane], w * xu);
}

extern "C" void kernel_launch(void* const* d_in, const int* in_sizes, int n_in,
                              void* d_out, int out_size, void* d_ws, size_t ws_size,
                              hipStream_t stream) {
    const float* user_emb = (const float*)d_in[0];
    const float* item_emb = (const float*)d_in[1];
    const float* ev       = (const float*)d_in[2];
    const int*   eu       = (const int*)d_in[3];
    const int*   ei       = (const int*)d_in[4];
    // d_in[5] = n_layers, fixed at 3 by setup_inputs(); hardcoded below.

    float* out = (float*)d_out;

    char* ws = (char*)d_ws;
    float* deg  = (float*)ws;                      // NUM_USERS floats
    // align scratch emb buffer to 512B
    size_t off = ((size_t)NUM_USERS * sizeof(float) + 511) & ~(size_t)511;
    float* bufA = (float*)(ws + off);              // [N_TOTAL][64] floats

    const size_t emb_bytes = (size_t)N_TOTAL * EMB_D * sizeof(float);

    // --- degree + inv sqrt ---
    hipMemsetAsync(deg, 0, NUM_USERS * sizeof(float), stream);
    deg_kernel<<<(NUM_EDGES + 255) / 256, 256, 0, stream>>>(ev, eu, deg);
    inv_kernel<<<(NUM_USERS + 255) / 256, 256, 0, stream>>>(deg);

    // SpMM launch config: 4 edges per 256-thread block
    const int edges_per_block = 256 / 64;
    const int grid = (NUM_EDGES + edges_per_block - 1) / edges_per_block;

    // --- layer 1: inputs -> out ---
    hipMemsetAsync(out, 0, emb_bytes, stream);
    spmm_kernel<<<grid, 256, 0, stream>>>(user_emb, item_emb, ev, eu, ei, deg, out);

    // --- layer 2: out -> bufA ---
    hipMemsetAsync(bufA, 0, emb_bytes, stream);
    spmm_kernel<<<grid, 256, 0, stream>>>(out, out + (size_t)NUM_USERS * EMB_D,
                                          ev, eu, ei, deg, bufA);

    // --- layer 3: bufA -> out ---
    hipMemsetAsync(out, 0, emb_bytes, stream);
    spmm_kernel<<<grid, 256, 0, stream>>>(bufA, bufA + (size_t)NUM_USERS * EMB_D,
                                          ev, eu, ei, deg, out);
}

// Round 2
// 1689.131 us; speedup vs baseline: 1.5134x; 1.5134x over previous
//
#include <hip/hip_runtime.h>

#define NUM_USERS 100000
#define NUM_ITEMS 50000
#define NUM_EDGES 2000000
#define EMB_D 64
#define N_TOTAL (NUM_USERS + NUM_ITEMS)
#define SCAN_BLOCKS ((N_TOTAL + 255) / 256)   // 586

// ---------------------------------------------------------------------------
// Pass 1: user degree sum + per-row (user and item) edge counts
// ---------------------------------------------------------------------------
__global__ void deg_count_kernel(const float* __restrict__ ev,
                                 const int* __restrict__ eu,
                                 const int* __restrict__ ei,
                                 float* __restrict__ deg,
                                 int* __restrict__ cnt) {
    int e = blockIdx.x * blockDim.x + threadIdx.x;
    if (e < NUM_EDGES) {
        int u = eu[e], it = ei[e];
        atomicAdd(&deg[u], ev[e]);
        atomicAdd(&cnt[u], 1);
        atomicAdd(&cnt[NUM_USERS + it], 1);
    }
}

// inv[u] = 1/sqrt(deg[u] + 1e-6), in place
__global__ void inv_kernel(float* __restrict__ deg) {
    int i = blockIdx.x * blockDim.x + threadIdx.x;
    if (i < NUM_USERS) {
        deg[i] = rsqrtf(deg[i] + 1e-6f);
    }
}

// ---------------------------------------------------------------------------
// Exclusive scan of cnt[N_TOTAL] -> row_ptr, in 3 stages
// ---------------------------------------------------------------------------
__global__ void scan1_kernel(const int* __restrict__ cnt,
                             int* __restrict__ excl,
                             int* __restrict__ bsum) {
    __shared__ int s[256];
    int i = blockIdx.x * 256 + threadIdx.x;
    int v = (i < N_TOTAL) ? cnt[i] : 0;
    s[threadIdx.x] = v;
    __syncthreads();
    for (int off = 1; off < 256; off <<= 1) {
        int t = (threadIdx.x >= off) ? s[threadIdx.x - off] : 0;
        __syncthreads();
        s[threadIdx.x] += t;
        __syncthreads();
    }
    if (i < N_TOTAL) excl[i] = s[threadIdx.x] - v;   // exclusive
    if (threadIdx.x == 255) bsum[blockIdx.x] = s[255];
}

__global__ void scan2_kernel(int* __restrict__ bsum) {
    if (blockIdx.x == 0 && threadIdx.x == 0) {
        int acc = 0;
        for (int i = 0; i < SCAN_BLOCKS; i++) {
            int t = bsum[i];
            bsum[i] = acc;
            acc += t;
        }
    }
}

__global__ void scan3_kernel(int* __restrict__ row_ptr,
                             int* __restrict__ cursor,
                             const int* __restrict__ bsum) {
    int i = blockIdx.x * 256 + threadIdx.x;
    if (i < N_TOTAL) {
        int v = row_ptr[i] + bsum[blockIdx.x];
        row_ptr[i] = v;
        cursor[i] = v;
    }
}

// ---------------------------------------------------------------------------
// Scatter edges into packed CSR: cw[pos] = (col, weight-bits)
// Row u gets source NUM_USERS+i; row NUM_USERS+i gets source u.
// ---------------------------------------------------------------------------
__global__ void scatter_kernel(const float* __restrict__ ev,
                               const int* __restrict__ eu,
                               const int* __restrict__ ei,
                               const float* __restrict__ inv,
                               int* __restrict__ cursor,
                               uint2* __restrict__ cw) {
    int e = blockIdx.x * blockDim.x + threadIdx.x;
    if (e < NUM_EDGES) {
        int u = eu[e], it = ei[e];
        float w = ev[e] * inv[u];
        unsigned wb = __float_as_uint(w);
        int p1 = atomicAdd(&cursor[u], 1);
        cw[p1] = make_uint2((unsigned)(NUM_USERS + it), wb);
        int p2 = atomicAdd(&cursor[NUM_USERS + it], 1);
        cw[p2] = make_uint2((unsigned)u, wb);
    }
}

// ---------------------------------------------------------------------------
// Gather SpMM: one 64-lane wave per destination row; lane = embedding dim.
// acc += w * src_row[lane] over the row's CSR segment; one coalesced store.
// in_u / in_i are either the two original inputs (layer 1) or two views of
// the previous layer's [N_TOTAL][64] buffer.
// ---------------------------------------------------------------------------
__global__ __launch_bounds__(256) void spmm_gather_kernel(
        const float* __restrict__ in_u,
        const float* __restrict__ in_i,
        const int* __restrict__ row_ptr,
        const int* __restrict__ cnt,
        const uint2* __restrict__ cw,
        float* __restrict__ out) {
    const int lane = threadIdx.x & 63;
    const int row = blockIdx.x * 4 + (threadIdx.x >> 6);
    if (row >= N_TOTAL) return;

    const int start = row_ptr[row];
    const int n = cnt[row];
    float acc = 0.0f;
    for (int k = 0; k < n; k++) {
        uint2 p = cw[start + k];
        int col = (int)p.x;
        float w = __uint_as_float(p.y);
        const float* src = (col < NUM_USERS)
                               ? (in_u + (size_t)col * EMB_D)
                               : (in_i + (size_t)(col - NUM_USERS) * EMB_D);
        acc = fmaf(w, src[lane], acc);
    }
    out[(size_t)row * EMB_D + lane] = acc;
}

extern "C" void kernel_launch(void* const* d_in, const int* in_sizes, int n_in,
                              void* d_out, int out_size, void* d_ws, size_t ws_size,
                              hipStream_t stream) {
    const float* user_emb = (const float*)d_in[0];
    const float* item_emb = (const float*)d_in[1];
    const float* ev       = (const float*)d_in[2];
    const int*   eu       = (const int*)d_in[3];
    const int*   ei       = (const int*)d_in[4];
    // d_in[5] = n_layers, fixed at 3 by setup_inputs(); hardcoded.

    float* out = (float*)d_out;

    // ---- workspace layout (all 512B-aligned) ----
    char* ws = (char*)d_ws;
    size_t off = 0;
    auto alloc = [&](size_t bytes) {
        char* p = ws + off;
        off = (off + bytes + 511) & ~(size_t)511;
        return p;
    };
    float* deg     = (float*)alloc(NUM_USERS * sizeof(float));
    int*   cnt     = (int*)  alloc(N_TOTAL * sizeof(int));
    int*   row_ptr = (int*)  alloc(N_TOTAL * sizeof(int));
    int*   cursor  = (int*)  alloc(N_TOTAL * sizeof(int));
    int*   bsum    = (int*)  alloc(SCAN_BLOCKS * sizeof(int));
    uint2* cw      = (uint2*)alloc((size_t)2 * NUM_EDGES * sizeof(uint2));
    float* bufA    = (float*)alloc((size_t)N_TOTAL * EMB_D * sizeof(float));

    // ---- build normalization + CSR (once per call) ----
    hipMemsetAsync(deg, 0, NUM_USERS * sizeof(float), stream);
    hipMemsetAsync(cnt, 0, N_TOTAL * sizeof(int), stream);

    deg_count_kernel<<<(NUM_EDGES + 255) / 256, 256, 0, stream>>>(ev, eu, ei, deg, cnt);
    inv_kernel<<<(NUM_USERS + 255) / 256, 256, 0, stream>>>(deg);

    scan1_kernel<<<SCAN_BLOCKS, 256, 0, stream>>>(cnt, row_ptr, bsum);
    scan2_kernel<<<1, 64, 0, stream>>>(bsum);
    scan3_kernel<<<SCAN_BLOCKS, 256, 0, stream>>>(row_ptr, cursor, bsum);

    scatter_kernel<<<(NUM_EDGES + 255) / 256, 256, 0, stream>>>(ev, eu, ei, deg, cursor, cw);

    // ---- 3 gather-SpMM layers ----
    const int grid = (N_TOTAL + 3) / 4;   // 4 rows (waves) per 256-thread block

    // layer 1: original inputs -> out
    spmm_gather_kernel<<<grid, 256, 0, stream>>>(user_emb, item_emb,
                                                 row_ptr, cnt, cw, out);
    // layer 2: out -> bufA
    spmm_gather_kernel<<<grid, 256, 0, stream>>>(out, out + (size_t)NUM_USERS * EMB_D,
                                                 row_ptr, cnt, cw, bufA);
    // layer 3: bufA -> out
    spmm_gather_kernel<<<grid, 256, 0, stream>>>(bufA, bufA + (size_t)NUM_USERS * EMB_D,
                                                 row_ptr, cnt, cw, out);
}

// Round 3
// 974.804 us; speedup vs baseline: 2.6224x; 1.7328x over previous
//
#include <hip/hip_runtime.h>

#define NUM_USERS 100000
#define NUM_ITEMS 50000
#define NUM_EDGES 2000000
#define EMB_D 64
#define N_TOTAL (NUM_USERS + NUM_ITEMS)
#define SCAN_BLOCKS ((N_TOTAL + 255) / 256)   // 586

// ---------------------------------------------------------------------------
// Pass 1: user degree sum + per-row (user and item) edge counts
// ---------------------------------------------------------------------------
__global__ void deg_count_kernel(const float* __restrict__ ev,
                                 const int* __restrict__ eu,
                                 const int* __restrict__ ei,
                                 float* __restrict__ deg,
                                 int* __restrict__ cnt) {
    int e = blockIdx.x * blockDim.x + threadIdx.x;
    if (e < NUM_EDGES) {
        int u = eu[e], it = ei[e];
        atomicAdd(&deg[u], ev[e]);
        atomicAdd(&cnt[u], 1);
        atomicAdd(&cnt[NUM_USERS + it], 1);
    }
}

// inv[u] = 1/sqrt(deg[u] + 1e-6), in place
__global__ void inv_kernel(float* __restrict__ deg) {
    int i = blockIdx.x * blockDim.x + threadIdx.x;
    if (i < NUM_USERS) {
        deg[i] = rsqrtf(deg[i] + 1e-6f);
    }
}

// ---------------------------------------------------------------------------
// Exclusive scan of cnt[N_TOTAL] -> row_ptr, in 3 stages
// ---------------------------------------------------------------------------
__global__ void scan1_kernel(const int* __restrict__ cnt,
                             int* __restrict__ excl,
                             int* __restrict__ bsum) {
    __shared__ int s[256];
    int i = blockIdx.x * 256 + threadIdx.x;
    int v = (i < N_TOTAL) ? cnt[i] : 0;
    s[threadIdx.x] = v;
    __syncthreads();
    for (int off = 1; off < 256; off <<= 1) {
        int t = (threadIdx.x >= off) ? s[threadIdx.x - off] : 0;
        __syncthreads();
        s[threadIdx.x] += t;
        __syncthreads();
    }
    if (i < N_TOTAL) excl[i] = s[threadIdx.x] - v;   // exclusive
    if (threadIdx.x == 255) bsum[blockIdx.x] = s[255];
}

__global__ void scan2_kernel(int* __restrict__ bsum) {
    if (blockIdx.x == 0 && threadIdx.x == 0) {
        int acc = 0;
        for (int i = 0; i < SCAN_BLOCKS; i++) {
            int t = bsum[i];
            bsum[i] = acc;
            acc += t;
        }
    }
}

__global__ void scan3_kernel(int* __restrict__ row_ptr,
                             int* __restrict__ cursor,
                             const int* __restrict__ bsum) {
    int i = blockIdx.x * 256 + threadIdx.x;
    if (i < N_TOTAL) {
        int v = row_ptr[i] + bsum[blockIdx.x];
        row_ptr[i] = v;
        cursor[i] = v;
    }
}

// ---------------------------------------------------------------------------
// Scatter edges into packed CSR: cw[pos] = (col, weight-bits)
// Row u gets source NUM_USERS+i; row NUM_USERS+i gets source u.
// ---------------------------------------------------------------------------
__global__ void scatter_kernel(const float* __restrict__ ev,
                               const int* __restrict__ eu,
                               const int* __restrict__ ei,
                               const float* __restrict__ inv,
                               int* __restrict__ cursor,
                               uint2* __restrict__ cw) {
    int e = blockIdx.x * blockDim.x + threadIdx.x;
    if (e < NUM_EDGES) {
        int u = eu[e], it = ei[e];
        float w = ev[e] * inv[u];
        unsigned wb = __float_as_uint(w);
        int p1 = atomicAdd(&cursor[u], 1);
        cw[p1] = make_uint2((unsigned)(NUM_USERS + it), wb);
        int p2 = atomicAdd(&cursor[NUM_USERS + it], 1);
        cw[p2] = make_uint2((unsigned)u, wb);
    }
}

// ---------------------------------------------------------------------------
// Gather SpMM with 4-way edge parallelism per wave.
// Wave = 4 subgroups x 16 lanes. Subgroup s handles edges k+s; lane-in-group
// l16 loads float4 covering dims [4*l16 .. 4*l16+3]. One wave instruction
// therefore gathers 4 full 256B source rows -> 4x the outstanding loads of
// the 1-edge-per-wave version. Cross-subgroup butterfly reduce at the end.
// ---------------------------------------------------------------------------
__global__ __launch_bounds__(256) void spmm_gather4_kernel(
        const float* __restrict__ in_u,
        const float* __restrict__ in_i,
        const int* __restrict__ row_ptr,
        const int* __restrict__ cnt,
        const uint2* __restrict__ cw,
        float* __restrict__ out) {
    const int lane = threadIdx.x & 63;
    const int row = blockIdx.x * 4 + (threadIdx.x >> 6);
    if (row >= N_TOTAL) return;

    const int sub = lane >> 4;      // 0..3: which edge in the group of 4
    const int l16 = lane & 15;      // float4 slot within the row

    const int start = row_ptr[row];
    const int n = cnt[row];

    float4 acc = make_float4(0.f, 0.f, 0.f, 0.f);
    #pragma unroll 2
    for (int k = 0; k < n; k += 4) {
        const int e = k + sub;
        const bool valid = (e < n);
        const uint2 p = cw[start + (valid ? e : 0)];
        const float w = valid ? __uint_as_float(p.y) : 0.0f;
        const int col = valid ? (int)p.x : 0;
        const float* src = (col < NUM_USERS)
                               ? (in_u + (size_t)col * EMB_D)
                               : (in_i + (size_t)(col - NUM_USERS) * EMB_D);
        const float4 s = *reinterpret_cast<const float4*>(src + 4 * l16);
        acc.x = fmaf(w, s.x, acc.x);
        acc.y = fmaf(w, s.y, acc.y);
        acc.z = fmaf(w, s.z, acc.z);
        acc.w = fmaf(w, s.w, acc.w);
    }

    // butterfly reduce across the 4 subgroups (lanes l16, l16+16, +32, +48)
    acc.x += __shfl_xor(acc.x, 32); acc.y += __shfl_xor(acc.y, 32);
    acc.z += __shfl_xor(acc.z, 32); acc.w += __shfl_xor(acc.w, 32);
    acc.x += __shfl_xor(acc.x, 16); acc.y += __shfl_xor(acc.y, 16);
    acc.z += __shfl_xor(acc.z, 16); acc.w += __shfl_xor(acc.w, 16);

    if (sub == 0) {
        *reinterpret_cast<float4*>(out + (size_t)row * EMB_D + 4 * l16) = acc;
    }
}

extern "C" void kernel_launch(void* const* d_in, const int* in_sizes, int n_in,
                              void* d_out, int out_size, void* d_ws, size_t ws_size,
                              hipStream_t stream) {
    const float* user_emb = (const float*)d_in[0];
    const float* item_emb = (const float*)d_in[1];
    const float* ev       = (const float*)d_in[2];
    const int*   eu       = (const int*)d_in[3];
    const int*   ei       = (const int*)d_in[4];
    // d_in[5] = n_layers, fixed at 3 by setup_inputs(); hardcoded.

    float* out = (float*)d_out;

    // ---- workspace layout (all 512B-aligned) ----
    char* ws = (char*)d_ws;
    size_t off = 0;
    auto alloc = [&](size_t bytes) {
        char* p = ws + off;
        off = (off + bytes + 511) & ~(size_t)511;
        return p;
    };
    float* deg     = (float*)alloc(NUM_USERS * sizeof(float));
    int*   cnt     = (int*)  alloc(N_TOTAL * sizeof(int));
    int*   row_ptr = (int*)  alloc(N_TOTAL * sizeof(int));
    int*   cursor  = (int*)  alloc(N_TOTAL * sizeof(int));
    int*   bsum    = (int*)  alloc(SCAN_BLOCKS * sizeof(int));
    uint2* cw      = (uint2*)alloc((size_t)2 * NUM_EDGES * sizeof(uint2));
    float* bufA    = (float*)alloc((size_t)N_TOTAL * EMB_D * sizeof(float));

    // ---- build normalization + CSR (once per call) ----
    hipMemsetAsync(deg, 0, NUM_USERS * sizeof(float), stream);
    hipMemsetAsync(cnt, 0, N_TOTAL * sizeof(int), stream);

    deg_count_kernel<<<(NUM_EDGES + 255) / 256, 256, 0, stream>>>(ev, eu, ei, deg, cnt);
    inv_kernel<<<(NUM_USERS + 255) / 256, 256, 0, stream>>>(deg);

    scan1_kernel<<<SCAN_BLOCKS, 256, 0, stream>>>(cnt, row_ptr, bsum);
    scan2_kernel<<<1, 64, 0, stream>>>(bsum);
    scan3_kernel<<<SCAN_BLOCKS, 256, 0, stream>>>(row_ptr, cursor, bsum);

    scatter_kernel<<<(NUM_EDGES + 255) / 256, 256, 0, stream>>>(ev, eu, ei, deg, cursor, cw);

    // ---- 3 gather-SpMM layers ----
    const int grid = (N_TOTAL + 3) / 4;   // 4 rows (waves) per 256-thread block

    // layer 1: original inputs -> out
    spmm_gather4_kernel<<<grid, 256, 0, stream>>>(user_emb, item_emb,
                                                  row_ptr, cnt, cw, out);
    // layer 2: out -> bufA
    spmm_gather4_kernel<<<grid, 256, 0, stream>>>(out, out + (size_t)NUM_USERS * EMB_D,
                                                  row_ptr, cnt, cw, bufA);
    // layer 3: bufA -> out
    spmm_gather4_kernel<<<grid, 256, 0, stream>>>(bufA, bufA + (size_t)NUM_USERS * EMB_D,
                                                  row_ptr, cnt, cw, out);
}